// Round 18
// baseline (32.805 us; speedup 1.0000x reference)
//
#include <hip/hip_runtime.h>
#include <stdint.h>

// AeTransformer_44839458570443: 3-NN inverse-distance interpolation + (tanh+1)/2.
// xyz1: [B,3,N] fp32, xyz2: [B,3,S] fp32, points2: [B,1,S] fp32 -> out [B,N] fp32.
//
// Selection bit-matches the reference fp32 expanded distance
//   d = (-2*((x*x'+y*y')+z*z') + ||q||^2) + ||p||^2   (fp32, no FMA)
// ordered by (d, index).
//
// Round 18 = Round 17 + (a) prep fused into knn3 (table computed in-block
// from xyz2, bit-identical values; removes a graph dispatch + ws round-trip),
// (b) LDS overlay: tileA [0,8K) lives all kernel; tile2 (pair-SoA) [8K,16K)
// is dead after phase A, so the 20KB key exchange overlays [8K,28K) guarded
// by a barrier. 36.8KB -> 28KB/block = 5 blocks/CU; __launch_bounds__(256,5)
// caps VGPR ~102 -> 5 waves/SIMD (R17 was double-capped at 4).
// PHASE A (proxy, pk-fma): Q=4 x split-4; per group of 8, packed distances +
//   min tree -> group min; 5 best (group-min | gid) keys/slot. Lemma: at most
//   3 groups can have min <= d3; 5 kept for margin.
// MERGE: wave w owns query-slot w; INS5-merges 3 partners' lists via LDS.
// PHASE C (LDS AoS gathers): proxy rescan of 40 survivors, 9-bit 6-slot
//   screen, exact replicated ref_d on 6, (d,idx) sort, replicated fp32
//   weight chain (proven R2-R17).
static constexpr int B = 4;
static constexpr int N = 65536;
static constexpr int S = 512;

typedef float float2v __attribute__((ext_vector_type(2)));

// Reference-replicated fp32 distance (numpy order, no contraction)
__device__ __forceinline__ float ref_d(float x1, float y1, float z1, float ssrc, float4 p) {
    float dot = __fadd_rn(__fadd_rn(__fmul_rn(x1, p.x), __fmul_rn(y1, p.y)),
                          __fmul_rn(z1, p.z));
    float t = __fmul_rn(dot, -2.0f);
    return __fadd_rn(__fadd_rn(t, ssrc), p.w);
}

#define CAS(da_, ia_, db_, ib_)                                     \
    {                                                               \
        bool sw_ = (db_ < da_) || ((db_ == da_) && (ib_ < ia_));    \
        float tda_ = sw_ ? db_ : da_;                               \
        int tia_ = sw_ ? ib_ : ia_;                                 \
        db_ = sw_ ? da_ : db_;                                      \
        ib_ = sw_ ? ia_ : ib_;                                      \
        da_ = tda_;                                                 \
        ia_ = tia_;                                                 \
    }

// sorted insert into ascending 5-list (named slots)
#define INS5L(A0, A1, A2, A3, A4, k)                                \
    {                                                               \
        float t4 = __builtin_amdgcn_fmed3f(A3, (k), A4);            \
        float t3 = __builtin_amdgcn_fmed3f(A2, (k), A3);            \
        float t2 = __builtin_amdgcn_fmed3f(A1, (k), A2);            \
        float t1 = __builtin_amdgcn_fmed3f(A0, (k), A1);            \
        A0 = fminf(A0, (k));                                        \
        A1 = t1; A2 = t2; A3 = t3; A4 = t4;                         \
    }

#define INS6(k)                                                     \
    {                                                               \
        float t5 = __builtin_amdgcn_fmed3f(m4, (k), m5);            \
        float t4 = __builtin_amdgcn_fmed3f(m3, (k), m4);            \
        float t3 = __builtin_amdgcn_fmed3f(m2, (k), m3);            \
        float t2 = __builtin_amdgcn_fmed3f(m1, (k), m2);            \
        float t1 = __builtin_amdgcn_fmed3f(m0, (k), m1);            \
        m0 = fminf(m0, (k));                                        \
        m1 = t1; m2 = t2; m3 = t3; m4 = t4; m5 = t5;                \
    }

// Packed phase-A body for one query slot; xs/ys/zs/ww are float2v[4] pairs
#define PK_PROC(NXP, NYP, NZP, CC, A0, A1, A2, A3, A4, gid)                   \
    {                                                                         \
        float2v e0 = __builtin_elementwise_fma(                               \
            NXP, xs[0], __builtin_elementwise_fma(                            \
                            NYP, ys[0],                                       \
                            __builtin_elementwise_fma(NZP, zs[0], ww[0])));   \
        float2v e1 = __builtin_elementwise_fma(                               \
            NXP, xs[1], __builtin_elementwise_fma(                            \
                            NYP, ys[1],                                       \
                            __builtin_elementwise_fma(NZP, zs[1], ww[1])));   \
        float2v e2 = __builtin_elementwise_fma(                               \
            NXP, xs[2], __builtin_elementwise_fma(                            \
                            NYP, ys[2],                                       \
                            __builtin_elementwise_fma(NZP, zs[2], ww[2])));   \
        float2v e3 = __builtin_elementwise_fma(                               \
            NXP, xs[3], __builtin_elementwise_fma(                            \
                            NYP, ys[3],                                       \
                            __builtin_elementwise_fma(NZP, zs[3], ww[3])));   \
        float2v mA = __builtin_elementwise_min(e0, e1);                       \
        float2v mB = __builtin_elementwise_min(e2, e3);                       \
        float2v mC = __builtin_elementwise_min(mA, mB);                       \
        float gm = fminf(mC.x, mC.y);                                         \
        uint32_t kb = (__float_as_uint(gm + CC) & maskA) | (uint32_t)(gid);   \
        float gkey = __uint_as_float(kb);                                     \
        INS5L(A0, A1, A2, A3, A4, gkey);                                      \
    }

// Merge 3 partner 5-lists (rows R..R+4, partner tids P0,P1,P2) into A-list
#define MERGE3(R, A0, A1, A2, A3, A4, P0, P1, P2)                             \
    {                                                                         \
        _Pragma("unroll") for (int j = 0; j < 5; ++j) {                       \
            float k0 = keys[(R) + j][P0];                                     \
            float k1 = keys[(R) + j][P1];                                     \
            float k2 = keys[(R) + j][P2];                                     \
            INS5L(A0, A1, A2, A3, A4, k0);                                    \
            INS5L(A0, A1, A2, A3, A4, k1);                                    \
            INS5L(A0, A1, A2, A3, A4, k2);                                    \
        }                                                                     \
    }

// Phase C + refine + epilogue for one query — all gathers from LDS AoS tile
#define PHASE_C(NX, NY, NZ, CC, X1, Y1, Z1, SS, K0, K1, K2, K3, K4, NOUT)     \
    {                                                                         \
        float m0 = 3.0e38f, m1 = 3.0e38f, m2 = 3.0e38f,                       \
              m3 = 3.0e38f, m4 = 3.0e38f, m5 = 3.0e38f;                       \
        float gkeys[5] = {K0, K1, K2, K3, K4};                                \
        _Pragma("unroll") for (int t = 0; t < 5; ++t) {                       \
            int gbase = (int)(__float_as_uint(gkeys[t]) & 63u) << 3;          \
            _Pragma("unroll") for (int j = 0; j < 8; ++j) {                   \
                float4 p = tileA[gbase + j]; /* divergent LDS gather */       \
                float e2 = fmaf(NX, p.x,                                      \
                                fmaf(NY, p.y, fmaf(NZ, p.z, p.w + CC)));      \
                float k = __uint_as_float((__float_as_uint(e2) & 0xFFFFFE00u) \
                                          | (uint32_t)(gbase + j));           \
                INS6(k);                                                      \
            }                                                                 \
        }                                                                     \
        int gi[6];                                                            \
        float dd[6];                                                          \
        gi[0] = (int)(__float_as_uint(m0) & 511u);                            \
        gi[1] = (int)(__float_as_uint(m1) & 511u);                            \
        gi[2] = (int)(__float_as_uint(m2) & 511u);                            \
        gi[3] = (int)(__float_as_uint(m3) & 511u);                            \
        gi[4] = (int)(__float_as_uint(m4) & 511u);                            \
        gi[5] = (int)(__float_as_uint(m5) & 511u);                            \
        _Pragma("unroll") for (int j = 0; j < 6; ++j)                         \
            dd[j] = ref_d(X1, Y1, Z1, SS, tileA[gi[j]]);                      \
        _Pragma("unroll") for (int pp = 0; pp < 3; ++pp)                      \
            _Pragma("unroll") for (int i = 4; i >= pp; --i)                   \
                CAS(dd[i], gi[i], dd[i + 1], gi[i + 1]);                      \
        const float EPS32 = 1e-8f;                                            \
        float r0 = __fdiv_rn(1.0f, __fadd_rn(dd[0], EPS32));                  \
        float r1 = __fdiv_rn(1.0f, __fadd_rn(dd[1], EPS32));                  \
        float r2 = __fdiv_rn(1.0f, __fadd_rn(dd[2], EPS32));                  \
        float rs = __fadd_rn(__fadd_rn(r0, r1), r2);                          \
        float w0 = __fdiv_rn(r0, rs);                                         \
        float w1 = __fdiv_rn(r1, rs);                                         \
        float w2 = __fdiv_rn(r2, rs);                                         \
        float interp = __fadd_rn(__fadd_rn(__fmul_rn(f[gi[0]], w0),           \
                                           __fmul_rn(f[gi[1]], w1)),          \
                                 __fmul_rn(f[gi[2]], w2));                    \
        float th = tanhf(interp);                                             \
        out[((size_t)b << 16) | (uint32_t)(NOUT)] =                           \
            __fmul_rn(__fadd_rn(th, 1.0f), 0.5f);                             \
    }

__global__ __launch_bounds__(256, 5) void knn3_kernel(const float* __restrict__ xyz1,
                                                      const float* __restrict__ xyz2,
                                                      const float* __restrict__ points2,
                                                      float* __restrict__ out) {
    // 28 KB pool: tileA [0,8K) lives whole kernel; tile2 [8K,16K) dead after
    // phase A; keys rows [8K,28K) overlay tile2 (barrier-guarded).
    __shared__ __align__(16) char smem[28672];
    float4* tileA = (float4*)smem;                       // AoS, phase C/refine
    float4* tile2 = (float4*)(smem + 8192);              // pair-SoA, phase A
    float (*keys)[256] = (float(*)[256])(smem + 8192);   // 20 rows x 256

    const int tid = threadIdx.x;
    const int lane = tid & 63;
    const int wid_u = __builtin_amdgcn_readfirstlane(tid >> 6);  // wave 0-3
    const int b = blockIdx.x >> 8;      // 256 blocks per batch
    const int base = (blockIdx.x & 255) << 8;  // block covers 256 queries

    // ---- fused prep: build both table layouts from xyz2 (bit-identical) ----
    {
        const float* p = xyz2 + (size_t)b * 3 * S;
        float* t2f = (float*)tile2;
#pragma unroll
        for (int r = 0; r < 2; ++r) {
            int s = tid + r * 256;
            float x = p[s], y = p[s + S], z = p[s + 2 * S];
            float c = __fadd_rn(__fadd_rn(__fmul_rn(x, x), __fmul_rn(y, y)),
                                __fmul_rn(z, z));
            tileA[s] = make_float4(x, y, z, c);
            int pp = s >> 1, h = s & 1;
            t2f[pp * 8 + 0 + h] = x;
            t2f[pp * 8 + 2 + h] = y;
            t2f[pp * 8 + 4 + h] = z;
            t2f[pp * 8 + 6 + h] = c;
        }
    }
    __syncthreads();

    // 4 query slots per lane: n_s = base + s*64 + lane (coalesced loads)
    const int n_0 = base + lane, n_1 = n_0 + 64, n_2 = n_0 + 128, n_3 = n_0 + 192;
    const float* q = xyz1 + (size_t)b * 3 * N;
    float x_0 = q[n_0], y_0 = q[n_0 + N], z_0 = q[n_0 + 2 * N];
    float x_1 = q[n_1], y_1 = q[n_1 + N], z_1 = q[n_1 + 2 * N];
    float x_2 = q[n_2], y_2 = q[n_2 + N], z_2 = q[n_2 + 2 * N];
    float x_3 = q[n_3], y_3 = q[n_3 + N], z_3 = q[n_3 + 2 * N];
#define MKC(s)                                                                     \
    float ss_##s = __fadd_rn(__fadd_rn(__fmul_rn(x_##s, x_##s),                    \
                                       __fmul_rn(y_##s, y_##s)),                   \
                             __fmul_rn(z_##s, z_##s));                             \
    float c_##s = ss_##s + 0.25f;                                                  \
    float nx_##s = -2.0f * x_##s, ny_##s = -2.0f * y_##s, nz_##s = -2.0f * z_##s;  \
    float2v nxp_##s = {nx_##s, nx_##s};                                            \
    float2v nyp_##s = {ny_##s, ny_##s};                                            \
    float2v nzp_##s = {nz_##s, nz_##s};
    MKC(0) MKC(1) MKC(2) MKC(3)
#undef MKC

    uint32_t maskA = 0xFFFFFFC0u;     // VGPR mask -> single v_and_or_b32
    asm volatile("" : "+v"(maskA));

    // ---- Phase A: scan own 16 groups (pk distances); 5 best per slot ----
    float A0 = 3.0e38f, A1 = 3.0e38f, A2 = 3.0e38f, A3 = 3.0e38f, A4 = 3.0e38f;
    float B0 = 3.0e38f, B1 = 3.0e38f, B2 = 3.0e38f, B3 = 3.0e38f, B4 = 3.0e38f;
    float C0 = 3.0e38f, C1 = 3.0e38f, C2 = 3.0e38f, C3 = 3.0e38f, C4 = 3.0e38f;
    float D0 = 3.0e38f, D1 = 3.0e38f, D2 = 3.0e38f, D3 = 3.0e38f, D4 = 3.0e38f;
    const int gid0 = wid_u << 4;
#pragma unroll 2
    for (int g = 0; g < 16; ++g) {
        const int gid = gid0 + g;
        // group = 4 candidate pairs = 8 float4 (pair-SoA), broadcast b128
        float2v xs[4], ys[4], zs[4], ww[4];
#pragma unroll
        for (int k = 0; k < 4; ++k) {
            float4 pa = tile2[gid * 8 + 2 * k];      // {x_e,x_o,y_e,y_o}
            float4 pb = tile2[gid * 8 + 2 * k + 1];  // {z_e,z_o,w_e,w_o}
            xs[k] = (float2v){pa.x, pa.y};
            ys[k] = (float2v){pa.z, pa.w};
            zs[k] = (float2v){pb.x, pb.y};
            ww[k] = (float2v){pb.z, pb.w};
        }
        PK_PROC(nxp_0, nyp_0, nzp_0, c_0, A0, A1, A2, A3, A4, gid);
        PK_PROC(nxp_1, nyp_1, nzp_1, c_1, B0, B1, B2, B3, B4, gid);
        PK_PROC(nxp_2, nyp_2, nzp_2, c_2, C0, C1, C2, C3, C4, gid);
        PK_PROC(nxp_3, nyp_3, nzp_3, c_3, D0, D1, D2, D3, D4, gid);
    }

    // tile2 is dead from here; keys overlay its space. Barrier first so no
    // wave is still reading tile2 when another starts writing keys.
    __syncthreads();

    // ---- publish all 20 keys ----
    keys[0][tid] = A0; keys[1][tid] = A1; keys[2][tid] = A2;
    keys[3][tid] = A3; keys[4][tid] = A4;
    keys[5][tid] = B0; keys[6][tid] = B1; keys[7][tid] = B2;
    keys[8][tid] = B3; keys[9][tid] = B4;
    keys[10][tid] = C0; keys[11][tid] = C1; keys[12][tid] = C2;
    keys[13][tid] = C3; keys[14][tid] = C4;
    keys[15][tid] = D0; keys[16][tid] = D1; keys[17][tid] = D2;
    keys[18][tid] = D3; keys[19][tid] = D4;
    __syncthreads();

    // ---- merge + phase C: wave w owns query slot w ----
    const float* f = points2 + (size_t)b * S;  // D = 1
    if (wid_u == 0) {
        MERGE3(0, A0, A1, A2, A3, A4, lane + 64, lane + 128, lane + 192);
        PHASE_C(nx_0, ny_0, nz_0, c_0, x_0, y_0, z_0, ss_0,
                A0, A1, A2, A3, A4, n_0);
    } else if (wid_u == 1) {
        MERGE3(5, B0, B1, B2, B3, B4, lane, lane + 128, lane + 192);
        PHASE_C(nx_1, ny_1, nz_1, c_1, x_1, y_1, z_1, ss_1,
                B0, B1, B2, B3, B4, n_1);
    } else if (wid_u == 2) {
        MERGE3(10, C0, C1, C2, C3, C4, lane, lane + 64, lane + 192);
        PHASE_C(nx_2, ny_2, nz_2, c_2, x_2, y_2, z_2, ss_2,
                C0, C1, C2, C3, C4, n_2);
    } else {
        MERGE3(15, D0, D1, D2, D3, D4, lane, lane + 64, lane + 128);
        PHASE_C(nx_3, ny_3, nz_3, c_3, x_3, y_3, z_3, ss_3,
                D0, D1, D2, D3, D4, n_3);
    }
}

extern "C" void kernel_launch(void* const* d_in, const int* in_sizes, int n_in,
                              void* d_out, int out_size, void* d_ws, size_t ws_size,
                              hipStream_t stream) {
    const float* xyz1 = (const float*)d_in[0];
    const float* xyz2 = (const float*)d_in[1];
    const float* points2 = (const float*)d_in[2];
    float* out = (float*)d_out;
    (void)d_ws; (void)ws_size;

    // Single fused kernel: 1024 blocks x 256 threads; block covers 256
    // queries (Q=4 per lane), candidates split 4 ways across the block's waves
    knn3_kernel<<<(B * N) / 256, 256, 0, stream>>>(xyz1, xyz2, points2, out);
}

// Round 19
// 31.783 us; speedup vs baseline: 1.0322x; 1.0322x over previous
//
#include <hip/hip_runtime.h>
#include <stdint.h>

// AeTransformer_44839458570443: 3-NN inverse-distance interpolation + (tanh+1)/2.
// xyz1: [B,3,N] fp32, xyz2: [B,3,S] fp32, points2: [B,1,S] fp32 -> out [B,N] fp32.
//
// Selection bit-matches the reference fp32 expanded distance
//   d = (-2*((x*x'+y*y')+z*z') + ||q||^2) + ||p||^2   (fp32, no FMA)
// ordered by (d, index).
//
// Round 19: Q=8 x split-4. Per-block phase-A LDS traffic is invariant (table
// read exactly once per block), so per-CU traffic = 512 b128 x blocks/CU.
// Q=8 halves the block count (512 blocks = 2/CU -> ~5us phase-A LDS vs R17's
// ~10us). __launch_bounds__(256,2) gives a 256-VGPR budget so the 8-slot
// state (~190 VGPR) does NOT spill (R7's failure cause removed). Occupancy
// 2 waves/SIMD; ILP from 8 interleaved insert chains covers latency.
// PHASE A (proxy, pk-fma): per group of 8, packed distances + min tree ->
//   group min; 5 best (group-min | gid) keys per slot. Lemma: at most 3
//   groups can have min <= d3; 5 kept for margin.
// MERGE: wave w owns slots 2w,2w+1; INS5-merges 3 partners' lists via LDS
//   (disjoint group ranges + unique gid bits -> merged min-5 == full min-5).
// PHASE C (LDS AoS gathers): proxy rescan of 40 survivors, 9-bit 6-slot
//   screen, exact replicated ref_d on 6, (d,idx) sort, replicated fp32
//   weight chain (proven R2-R18).
static constexpr int B = 4;
static constexpr int N = 65536;
static constexpr int S = 512;

typedef float float2v __attribute__((ext_vector_type(2)));

// Reference-replicated fp32 distance (numpy order, no contraction)
__device__ __forceinline__ float ref_d(float x1, float y1, float z1, float ssrc, float4 p) {
    float dot = __fadd_rn(__fadd_rn(__fmul_rn(x1, p.x), __fmul_rn(y1, p.y)),
                          __fmul_rn(z1, p.z));
    float t = __fmul_rn(dot, -2.0f);
    return __fadd_rn(__fadd_rn(t, ssrc), p.w);
}

#define CAS(da_, ia_, db_, ib_)                                     \
    {                                                               \
        bool sw_ = (db_ < da_) || ((db_ == da_) && (ib_ < ia_));    \
        float tda_ = sw_ ? db_ : da_;                               \
        int tia_ = sw_ ? ib_ : ia_;                                 \
        db_ = sw_ ? da_ : db_;                                      \
        ib_ = sw_ ? ia_ : ib_;                                      \
        da_ = tda_;                                                 \
        ia_ = tia_;                                                 \
    }

// sorted insert into ascending 5-list (named slots)
#define INS5L(A0, A1, A2, A3, A4, k)                                \
    {                                                               \
        float t4 = __builtin_amdgcn_fmed3f(A3, (k), A4);            \
        float t3 = __builtin_amdgcn_fmed3f(A2, (k), A3);            \
        float t2 = __builtin_amdgcn_fmed3f(A1, (k), A2);            \
        float t1 = __builtin_amdgcn_fmed3f(A0, (k), A1);            \
        A0 = fminf(A0, (k));                                        \
        A1 = t1; A2 = t2; A3 = t3; A4 = t4;                         \
    }

#define INS6(k)                                                     \
    {                                                               \
        float t5 = __builtin_amdgcn_fmed3f(m4, (k), m5);            \
        float t4 = __builtin_amdgcn_fmed3f(m3, (k), m4);            \
        float t3 = __builtin_amdgcn_fmed3f(m2, (k), m3);            \
        float t2 = __builtin_amdgcn_fmed3f(m1, (k), m2);            \
        float t1 = __builtin_amdgcn_fmed3f(m0, (k), m1);            \
        m0 = fminf(m0, (k));                                        \
        m1 = t1; m2 = t2; m3 = t3; m4 = t4; m5 = t5;                \
    }

// Packed phase-A body for slot s; xs/ys/zs/ww are float2v[4] pairs
#define PK_PROC(s, gid)                                                       \
    {                                                                         \
        float2v e0 = __builtin_elementwise_fma(                               \
            nxp_##s, xs[0], __builtin_elementwise_fma(                        \
                                nyp_##s, ys[0],                               \
                                __builtin_elementwise_fma(nzp_##s, zs[0],     \
                                                          ww[0])));           \
        float2v e1 = __builtin_elementwise_fma(                               \
            nxp_##s, xs[1], __builtin_elementwise_fma(                        \
                                nyp_##s, ys[1],                               \
                                __builtin_elementwise_fma(nzp_##s, zs[1],     \
                                                          ww[1])));           \
        float2v e2 = __builtin_elementwise_fma(                               \
            nxp_##s, xs[2], __builtin_elementwise_fma(                        \
                                nyp_##s, ys[2],                               \
                                __builtin_elementwise_fma(nzp_##s, zs[2],     \
                                                          ww[2])));           \
        float2v e3 = __builtin_elementwise_fma(                               \
            nxp_##s, xs[3], __builtin_elementwise_fma(                        \
                                nyp_##s, ys[3],                               \
                                __builtin_elementwise_fma(nzp_##s, zs[3],     \
                                                          ww[3])));           \
        float2v mA = __builtin_elementwise_min(e0, e1);                       \
        float2v mB = __builtin_elementwise_min(e2, e3);                       \
        float2v mC = __builtin_elementwise_min(mA, mB);                       \
        float gm = fminf(mC.x, mC.y);                                         \
        uint32_t kb = (__float_as_uint(gm + c_##s) & maskA) | (uint32_t)(gid);\
        float gkey = __uint_as_float(kb);                                     \
        INS5L(k##s##0, k##s##1, k##s##2, k##s##3, k##s##4, gkey);             \
    }

// Phase C + refine + epilogue for slot s
#define PHASE_C(s)                                                            \
    {                                                                         \
        float m0 = 3.0e38f, m1 = 3.0e38f, m2 = 3.0e38f,                       \
              m3 = 3.0e38f, m4 = 3.0e38f, m5 = 3.0e38f;                       \
        float gkeys[5] = {k##s##0, k##s##1, k##s##2, k##s##3, k##s##4};       \
        _Pragma("unroll") for (int t = 0; t < 5; ++t) {                       \
            int gbase = (int)(__float_as_uint(gkeys[t]) & 63u) << 3;          \
            _Pragma("unroll") for (int j = 0; j < 8; ++j) {                   \
                float4 p = tileA[gbase + j]; /* divergent LDS gather */       \
                float e2 = fmaf(nx_##s, p.x,                                  \
                                fmaf(ny_##s, p.y,                             \
                                     fmaf(nz_##s, p.z, p.w + c_##s)));        \
                float k = __uint_as_float((__float_as_uint(e2) & 0xFFFFFE00u) \
                                          | (uint32_t)(gbase + j));           \
                INS6(k);                                                      \
            }                                                                 \
        }                                                                     \
        int gi[6];                                                            \
        float dd[6];                                                          \
        gi[0] = (int)(__float_as_uint(m0) & 511u);                            \
        gi[1] = (int)(__float_as_uint(m1) & 511u);                            \
        gi[2] = (int)(__float_as_uint(m2) & 511u);                            \
        gi[3] = (int)(__float_as_uint(m3) & 511u);                            \
        gi[4] = (int)(__float_as_uint(m4) & 511u);                            \
        gi[5] = (int)(__float_as_uint(m5) & 511u);                            \
        _Pragma("unroll") for (int j = 0; j < 6; ++j)                         \
            dd[j] = ref_d(x_##s, y_##s, z_##s, ss_##s, tileA[gi[j]]);         \
        _Pragma("unroll") for (int pp = 0; pp < 3; ++pp)                      \
            _Pragma("unroll") for (int i = 4; i >= pp; --i)                   \
                CAS(dd[i], gi[i], dd[i + 1], gi[i + 1]);                      \
        const float EPS32 = 1e-8f;                                            \
        float r0 = __fdiv_rn(1.0f, __fadd_rn(dd[0], EPS32));                  \
        float r1 = __fdiv_rn(1.0f, __fadd_rn(dd[1], EPS32));                  \
        float r2 = __fdiv_rn(1.0f, __fadd_rn(dd[2], EPS32));                  \
        float rs = __fadd_rn(__fadd_rn(r0, r1), r2);                          \
        float w0 = __fdiv_rn(r0, rs);                                         \
        float w1 = __fdiv_rn(r1, rs);                                         \
        float w2 = __fdiv_rn(r2, rs);                                         \
        float interp = __fadd_rn(__fadd_rn(__fmul_rn(f[gi[0]], w0),           \
                                           __fmul_rn(f[gi[1]], w1)),          \
                                 __fmul_rn(f[gi[2]], w2));                    \
        float th = tanhf(interp);                                             \
        out[((size_t)b << 16) | (uint32_t)(n_0 + 64 * (s))] =                 \
            __fmul_rn(__fadd_rn(th, 1.0f), 0.5f);                             \
    }

// Merge 3 partner lists for slot s (partner wave bases P0,P1,P2) + phase C
#define FIN(s, P0, P1, P2)                                                    \
    {                                                                         \
        _Pragma("unroll") for (int j = 0; j < 5; ++j) {                       \
            float q0 = keys[(s) * 5 + j][lane + (P0)];                        \
            float q1 = keys[(s) * 5 + j][lane + (P1)];                        \
            float q2 = keys[(s) * 5 + j][lane + (P2)];                        \
            INS5L(k##s##0, k##s##1, k##s##2, k##s##3, k##s##4, q0);           \
            INS5L(k##s##0, k##s##1, k##s##2, k##s##3, k##s##4, q1);           \
            INS5L(k##s##0, k##s##1, k##s##2, k##s##3, k##s##4, q2);           \
        }                                                                     \
        PHASE_C(s);                                                           \
    }

__global__ __launch_bounds__(256, 2) void knn3_kernel(const float* __restrict__ xyz1,
                                                      const float* __restrict__ xyz2,
                                                      const float* __restrict__ points2,
                                                      float* __restrict__ out) {
    // 48 KB pool: tileA [0,8K) whole kernel; tile2 [8K,16K) dead after phase
    // A; keys rows (40 x 256 floats = 40K) overlay [8K,48K), barrier-guarded.
    __shared__ __align__(16) char smem[49152];
    float4* tileA = (float4*)smem;                       // AoS, phase C/refine
    float4* tile2 = (float4*)(smem + 8192);              // pair-SoA, phase A
    float (*keys)[256] = (float(*)[256])(smem + 8192);   // 40 rows x 256

    const int tid = threadIdx.x;
    const int lane = tid & 63;
    const int wid_u = __builtin_amdgcn_readfirstlane(tid >> 6);  // wave 0-3
    const int b = blockIdx.x >> 7;             // 128 blocks per batch
    const int base = (blockIdx.x & 127) << 9;  // block covers 512 queries

    // ---- fused prep: build both table layouts from xyz2 (bit-identical) ----
    {
        const float* p = xyz2 + (size_t)b * 3 * S;
        float* t2f = (float*)tile2;
#pragma unroll
        for (int r = 0; r < 2; ++r) {
            int s = tid + r * 256;
            float x = p[s], y = p[s + S], z = p[s + 2 * S];
            float c = __fadd_rn(__fadd_rn(__fmul_rn(x, x), __fmul_rn(y, y)),
                                __fmul_rn(z, z));
            tileA[s] = make_float4(x, y, z, c);
            int pp = s >> 1, h = s & 1;
            t2f[pp * 8 + 0 + h] = x;
            t2f[pp * 8 + 2 + h] = y;
            t2f[pp * 8 + 4 + h] = z;
            t2f[pp * 8 + 6 + h] = c;
        }
    }
    __syncthreads();

    // 8 query slots per lane: n_s = base + s*64 + lane (coalesced loads)
    const int n_0 = base + lane;
    const float* q = xyz1 + (size_t)b * 3 * N;
#define MKC(s)                                                                     \
    float x_##s = q[n_0 + 64 * s], y_##s = q[n_0 + 64 * s + N],                    \
          z_##s = q[n_0 + 64 * s + 2 * N];                                         \
    float ss_##s = __fadd_rn(__fadd_rn(__fmul_rn(x_##s, x_##s),                    \
                                       __fmul_rn(y_##s, y_##s)),                   \
                             __fmul_rn(z_##s, z_##s));                             \
    float c_##s = ss_##s + 0.25f;                                                  \
    float nx_##s = -2.0f * x_##s, ny_##s = -2.0f * y_##s, nz_##s = -2.0f * z_##s;  \
    float2v nxp_##s = {nx_##s, nx_##s};                                            \
    float2v nyp_##s = {ny_##s, ny_##s};                                            \
    float2v nzp_##s = {nz_##s, nz_##s};                                            \
    float k##s##0 = 3.0e38f, k##s##1 = 3.0e38f, k##s##2 = 3.0e38f,                 \
          k##s##3 = 3.0e38f, k##s##4 = 3.0e38f;
    MKC(0) MKC(1) MKC(2) MKC(3) MKC(4) MKC(5) MKC(6) MKC(7)
#undef MKC

    uint32_t maskA = 0xFFFFFFC0u;     // VGPR mask -> single v_and_or_b32
    asm volatile("" : "+v"(maskA));

    // ---- Phase A: scan own 16 groups (pk distances); 5 best per slot ----
    const int gid0 = wid_u << 4;
#pragma unroll 2
    for (int g = 0; g < 16; ++g) {
        const int gid = gid0 + g;
        // group = 4 candidate pairs = 8 float4 (pair-SoA), broadcast b128
        float2v xs[4], ys[4], zs[4], ww[4];
#pragma unroll
        for (int k = 0; k < 4; ++k) {
            float4 pa = tile2[gid * 8 + 2 * k];      // {x_e,x_o,y_e,y_o}
            float4 pb = tile2[gid * 8 + 2 * k + 1];  // {z_e,z_o,w_e,w_o}
            xs[k] = (float2v){pa.x, pa.y};
            ys[k] = (float2v){pa.z, pa.w};
            zs[k] = (float2v){pb.x, pb.y};
            ww[k] = (float2v){pb.z, pb.w};
        }
        PK_PROC(0, gid) PK_PROC(1, gid) PK_PROC(2, gid) PK_PROC(3, gid)
        PK_PROC(4, gid) PK_PROC(5, gid) PK_PROC(6, gid) PK_PROC(7, gid)
    }

    // tile2 dead; keys overlay its space. Barrier so no wave still reads it.
    __syncthreads();

    // ---- publish all 40 keys ----
#define PUB(s)                                                       \
    keys[s * 5 + 0][tid] = k##s##0; keys[s * 5 + 1][tid] = k##s##1;  \
    keys[s * 5 + 2][tid] = k##s##2; keys[s * 5 + 3][tid] = k##s##3;  \
    keys[s * 5 + 4][tid] = k##s##4;
    PUB(0) PUB(1) PUB(2) PUB(3) PUB(4) PUB(5) PUB(6) PUB(7)
#undef PUB
    __syncthreads();

    // ---- merge + phase C: wave w owns slots 2w, 2w+1 ----
    const float* f = points2 + (size_t)b * S;  // D = 1
    if (wid_u == 0) {
        FIN(0, 64, 128, 192)
        FIN(1, 64, 128, 192)
    } else if (wid_u == 1) {
        FIN(2, 0, 128, 192)
        FIN(3, 0, 128, 192)
    } else if (wid_u == 2) {
        FIN(4, 0, 64, 192)
        FIN(5, 0, 64, 192)
    } else {
        FIN(6, 0, 64, 128)
        FIN(7, 0, 64, 128)
    }
}

extern "C" void kernel_launch(void* const* d_in, const int* in_sizes, int n_in,
                              void* d_out, int out_size, void* d_ws, size_t ws_size,
                              hipStream_t stream) {
    const float* xyz1 = (const float*)d_in[0];
    const float* xyz2 = (const float*)d_in[1];
    const float* points2 = (const float*)d_in[2];
    float* out = (float*)d_out;
    (void)d_ws; (void)ws_size;

    // 512 blocks x 256 threads: block covers 512 queries (Q=8 per lane),
    // candidates split 4 ways across the block's waves
    knn3_kernel<<<(B * N) / 512, 256, 0, stream>>>(xyz1, xyz2, points2, out);
}